// Round 4
// baseline (4648.580 us; speedup 1.0000x reference)
//
#include <hip/hip_runtime.h>

// RNN: h[t] = tanh(W_h h[t-1] + W_x x[t] + b), out = stacked h (fp32).
//  prep_pack : W_h -> f16 packed Whpk[p*512 + r] = row r, k-group p (8 f16, 16B).
//  xin_gemm  : f16 MFMA GEMM writes u = x@W_x^T + b INTO d_out.
//  rnn_scan  : 64 wgs (1/batch), 512 thr; thread r owns row r (R2 structure).
//              W_h split: 7 k8-groups LDS (56 KiB), 32 groups PINNED IN AGPRS
//              (128 regs, def/use both class-constrained so regalloc cannot
//              spill), 25 streamed from L2 in 3 pipelined chunks (9/8/8).
//              u[t+1] prefetched a step ahead; double-buffered f16 h state ->
//              single barrier/step. Fast tanh via v_exp_f32.

typedef _Float16 h2      __attribute__((ext_vector_type(2)));
typedef _Float16 half4_t __attribute__((ext_vector_type(4)));
typedef _Float16 half8_t __attribute__((ext_vector_type(8)));
typedef float    f32x4   __attribute__((ext_vector_type(4)));

#define T_STEPS 1024
#define B_SZ    64
#define NIN     128
#define NH      512
#define WCOLS   641        // NH + NIN + 1
#define LCACHE  7          // k8-groups in LDS
#define ACACHE  32         // k8-groups in AGPRs (128 regs)
// group map: LDS = 0..6, AGPR = 7..38, STREAM = 39..63 (25 groups: 9+8+8)

__device__ __forceinline__ float fdot2_(h2 a, h2 b, float c) {
#if __has_builtin(__builtin_amdgcn_fdot2)
    return __builtin_amdgcn_fdot2(a, b, c, false);
#else
    return c + (float)a.x * (float)b.x + (float)a.y * (float)b.y;
#endif
}

__device__ __forceinline__ float dot8(uint4 wu, uint4 hu, float acc) {
    union { uint4 u; h2 h[4]; } w, hv;
    w.u = wu; hv.u = hu;
    acc = fdot2_(w.h[0], hv.h[0], acc);
    acc = fdot2_(w.h[1], hv.h[1], acc);
    acc = fdot2_(w.h[2], hv.h[2], acc);
    acc = fdot2_(w.h[3], hv.h[3], acc);
    return acc;
}

// ---- AGPR-resident storage: def and use both class-constrained ----
struct agpr4 { unsigned x, y, z, w; };   // lives in 4 AGPRs

__device__ __forceinline__ void apin(agpr4& d, uint4 s) {
    asm volatile("v_accvgpr_write_b32 %0, %1" : "=a"(d.x) : "v"(s.x));
    asm volatile("v_accvgpr_write_b32 %0, %1" : "=a"(d.y) : "v"(s.y));
    asm volatile("v_accvgpr_write_b32 %0, %1" : "=a"(d.z) : "v"(s.z));
    asm volatile("v_accvgpr_write_b32 %0, %1" : "=a"(d.w) : "v"(s.w));
}
__device__ __forceinline__ uint4 aget(const agpr4& s) {
    uint4 d;
    asm volatile("v_accvgpr_read_b32 %0, %1" : "=v"(d.x) : "a"(s.x));
    asm volatile("v_accvgpr_read_b32 %0, %1" : "=v"(d.y) : "a"(s.y));
    asm volatile("v_accvgpr_read_b32 %0, %1" : "=v"(d.z) : "a"(s.z));
    asm volatile("v_accvgpr_read_b32 %0, %1" : "=v"(d.w) : "a"(s.w));
    return d;
}

__device__ __forceinline__ float fast_tanh(float x) {
    float z = x * 2.8853900817779268f;        // 2/ln2
#if __has_builtin(__builtin_amdgcn_exp2f)
    float e = __builtin_amdgcn_exp2f(z);
#else
    float e = exp2f(z);
#endif
#if __has_builtin(__builtin_amdgcn_rcpf)
    return 1.f - 2.f * __builtin_amdgcn_rcpf(e + 1.f);
#else
    return 1.f - 2.f / (e + 1.f);
#endif
}

// ---------------- prep: pack W_h f16, layout Whpk[p*512 + r] ----------------
__global__ void prep_pack(const float* __restrict__ w_rec,
                          uint4* __restrict__ Whpk) {
    int o = blockIdx.x * 256 + threadIdx.x;   // 0..32767 = p*512 + r
    int r = o & 511, p = o >> 9;
    union { uint4 u; _Float16 f[8]; } pk;
#pragma unroll
    for (int e = 0; e < 8; ++e)
        pk.f[e] = (_Float16)w_rec[r * WCOLS + 8 * p + e];
    Whpk[o] = pk.u;
}

// ---------------- xin GEMM (f16 MFMA): u = x @ W_x^T + b -> d_out ----------------
// tile M=64 x N=128, K=128. 256 thr = 4 waves; wave w -> cols w*32..w*32+31.
__global__ __launch_bounds__(256) void xin_gemm(const float* __restrict__ x,
                                                const float* __restrict__ w_rec,
                                                float* __restrict__ out) {
    __shared__ _Float16 xs[64][136];    // +8 pad
    __shared__ _Float16 ws[128][136];
    const int tid = threadIdx.x;
    const int m0 = blockIdx.x * 64;
    const int n0 = blockIdx.y * 128;

#pragma unroll
    for (int c = 0; c < 8; ++c) {
        int f = tid + 256 * c;                 // 0..2047
        int row = f >> 5, c4 = (f & 31) * 4;
        float4 v = *(const float4*)(x + (long)(m0 + row) * NIN + c4);
        half4_t hv = {(_Float16)v.x, (_Float16)v.y, (_Float16)v.z, (_Float16)v.w};
        *(half4_t*)&xs[row][c4] = hv;
    }
#pragma unroll
    for (int c = 0; c < 16; ++c) {
        int f = tid + 256 * c;                 // 0..4095
        int row = f >> 5, c4 = (f & 31) * 4;
        const float* src = w_rec + (long)(n0 + row) * WCOLS + NH + c4;
        half4_t hv = {(_Float16)src[0], (_Float16)src[1], (_Float16)src[2], (_Float16)src[3]};
        *(half4_t*)&ws[row][c4] = hv;
    }
    __syncthreads();

    const int lane = tid & 63, w = tid >> 6;
    const int lr = lane & 15, lc = lane >> 4;
    f32x4 acc[4][2];
#pragma unroll
    for (int mi = 0; mi < 4; ++mi)
#pragma unroll
        for (int ni = 0; ni < 2; ++ni) acc[mi][ni] = (f32x4){0.f, 0.f, 0.f, 0.f};

#pragma unroll
    for (int ki = 0; ki < 4; ++ki) {
        int k0 = ki * 32 + lc * 8;
        half8_t a[4], bf[2];
#pragma unroll
        for (int mi = 0; mi < 4; ++mi) a[mi] = *(half8_t*)&xs[mi * 16 + lr][k0];
#pragma unroll
        for (int ni = 0; ni < 2; ++ni) bf[ni] = *(half8_t*)&ws[w * 32 + ni * 16 + lr][k0];
#pragma unroll
        for (int mi = 0; mi < 4; ++mi)
#pragma unroll
            for (int ni = 0; ni < 2; ++ni)
                acc[mi][ni] = __builtin_amdgcn_mfma_f32_16x16x32_f16(
                    a[mi], bf[ni], acc[mi][ni], 0, 0, 0);
    }
    // C/D layout: col=lane&15, row=(lane>>4)*4+reg (m89/m91-verified)
#pragma unroll
    for (int ni = 0; ni < 2; ++ni) {
        int col = n0 + w * 32 + ni * 16 + lr;
        float bv = w_rec[(long)col * WCOLS + NH + NIN];
#pragma unroll
        for (int mi = 0; mi < 4; ++mi)
#pragma unroll
            for (int r = 0; r < 4; ++r) {
                long row = m0 + mi * 16 + lc * 4 + r;
                out[row * NH + col] = acc[mi][ni][r] + bv;
            }
    }
}

// ---------------- serial scan: one workgroup per batch element ----------------
__global__ __launch_bounds__(512, 2) void rnn_scan(float* __restrict__ out,
                                                   const float* __restrict__ h0,
                                                   const uint4* __restrict__ Whpk) {
    __shared__ uint4 Wl[LCACHE * NH];   // 56 KiB: groups 0..6
    __shared__ uint4 hh[2][NH / 8];     // double-buffered f16 h state, 2 KiB

    const int tid = threadIdx.x;        // = output row r
    const int b   = blockIdx.x;

#pragma unroll
    for (int j = 0; j < LCACHE; ++j) Wl[j * NH + tid] = Whpk[j * NH + tid];

    agpr4 Wa[ACACHE];                   // groups 7..38 live in AGPRs
#pragma unroll
    for (int i = 0; i < ACACHE; ++i)
        apin(Wa[i], Whpk[(LCACHE + i) * NH + tid]);

    ((_Float16*)hh[0])[tid] = (_Float16)h0[b * NH + tid];
    __syncthreads();

    float* pu = out + (long)b * NH + tid;   // u/h slot for (t, b, r)
    float u_cur = *pu;

    for (int t = 0; t < T_STEPS; ++t) {
        const uint4* hcur = hh[t & 1];
        float acc[4];
        acc[0] = u_cur; acc[1] = 0.f; acc[2] = 0.f; acc[3] = 0.f;

        uint4 bufA[9], bufB[8];
        // issue stream chunk A: groups 39..47
#pragma unroll
        for (int i = 0; i < 9; ++i) bufA[i] = Whpk[(39 + i) * NH + tid];
        // prefetch next step's u
        long stride = (t + 1 < T_STEPS) ? (long)B_SZ * NH : 0;
        float u_nxt = pu[stride];
        // AGPR groups 7..22 while chunk A is in flight
#pragma unroll
        for (int i = 0; i < 16; ++i)
            acc[i & 3] = dot8(aget(Wa[i]), hcur[LCACHE + i], acc[i & 3]);
        // issue chunk B: groups 48..55; consume A
#pragma unroll
        for (int i = 0; i < 8; ++i) bufB[i] = Whpk[(48 + i) * NH + tid];
#pragma unroll
        for (int i = 0; i < 9; ++i)
            acc[i & 3] = dot8(bufA[i], hcur[39 + i], acc[i & 3]);
        // AGPR groups 23..38
#pragma unroll
        for (int i = 16; i < 32; ++i)
            acc[i & 3] = dot8(aget(Wa[i]), hcur[LCACHE + i], acc[i & 3]);
        // issue chunk C: groups 56..63; consume B
#pragma unroll
        for (int i = 0; i < 8; ++i) bufA[i] = Whpk[(56 + i) * NH + tid];
#pragma unroll
        for (int i = 0; i < 8; ++i)
            acc[i & 3] = dot8(bufB[i], hcur[48 + i], acc[i & 3]);
        // LDS groups 0..6
#pragma unroll
        for (int i = 0; i < 7; ++i)
            acc[i & 3] = dot8(Wl[i * NH + tid], hcur[i], acc[i & 3]);
        // consume C
#pragma unroll
        for (int i = 0; i < 8; ++i)
            acc[i & 3] = dot8(bufA[i], hcur[56 + i], acc[i & 3]);

        float hnew = fast_tanh((acc[0] + acc[1]) + (acc[2] + acc[3]));
        *pu = hnew;                                       // fp32 out (in place)
        ((_Float16*)hh[(t + 1) & 1])[tid] = (_Float16)hnew;
        u_cur = u_nxt;
        pu += B_SZ * NH;
        __syncthreads();   // hh next visible; reads of hcur done
    }
}

extern "C" void kernel_launch(void* const* d_in, const int* in_sizes, int n_in,
                              void* d_out, int out_size, void* d_ws, size_t ws_size,
                              hipStream_t stream) {
    const float* x     = (const float*)d_in[0];   // (1024,64,128)
    const float* h0    = (const float*)d_in[1];   // (64,512)
    const float* w_rec = (const float*)d_in[2];   // (512,641)
    float* out = (float*)d_out;                   // (1024,64,512)

    uint4* Whpk = (uint4*)d_ws;                   // 512 KiB packed W_h (f16)

    prep_pack<<<128, 256, 0, stream>>>(w_rec, Whpk);

    dim3 gA(T_STEPS * B_SZ / 64, NH / 128);       // 1024 x 4
    xin_gemm<<<gA, 256, 0, stream>>>(x, w_rec, out);

    rnn_scan<<<B_SZ, NH, 0, stream>>>(out, h0, Whpk);
}